// Round 13
// baseline (228.463 us; speedup 1.0000x reference)
//
#include <hip/hip_runtime.h>

#define S_  512
#define B_  256
#define NIN 180

typedef float v2 __attribute__((ext_vector_type(2)));

#define SSIG  -1.4426950408889634f
#define STANH -2.8853900817779268f

// ---- DPP ctrl encodings (verified on HW r5-r12) ----
#define QP_X1 0xB1
#define QP_X2 0x4E
#define QP_X3 0x1B
#define ROR4  0x124
#define ROR8  0x128

template<int CTRL>
__device__ __forceinline__ float dppf(float x) {
    return __uint_as_float((unsigned)__builtin_amdgcn_update_dpp(
        0, (int)__float_as_uint(x), CTRL, 0xF, 0xF, true));
}

#define ROTS8(h, r) do { \
    r[0] = (h); \
    r[1] = dppf<QP_X1>(h); \
    r[2] = dppf<QP_X2>(h); \
    r[3] = dppf<QP_X3>(h); \
    r[4] = dppf<ROR4>(h); \
    r[5] = dppf<QP_X1>(r[4]); \
    r[6] = dppf<QP_X2>(r[4]); \
    r[7] = dppf<QP_X3>(r[4]); \
} while (0)

// Fused kernel: blocks 0..63 = scan (4 waves: A1 layer0, A2 a1p, B layer1,
// W3 projection); blocks 64..255 = xg producers (1024 half-s items, flagged).
__global__ __launch_bounds__(256, 2) void lstm_fused(
    const float* __restrict__ x,
    const float* __restrict__ w_ih0, const float* __restrict__ b_ih0,
    const float* __restrict__ b_hh0, const float* __restrict__ w_hh0,
    const float* __restrict__ w_ih1, const float* __restrict__ w_hh1,
    const float* __restrict__ b_ih1, const float* __restrict__ b_hh1,
    const float* __restrict__ w_reg, const float* __restrict__ b_reg,
    float* __restrict__ xg2, unsigned* __restrict__ flags,
    float* __restrict__ out)
{
    __shared__ float ring0[16][64];    // h0(u) at slot u&15
    __shared__ float ring1[16][128];   // a1p(u) (v2) at slot u&15
    __shared__ float ring2[16][64];    // h1(u) at slot u&15
    __shared__ float wt[NIN][32];
    __shared__ float bias[32];

    const int bid = blockIdx.x;
    const int tid = threadIdx.x;

    if (bid >= 64) {
        // ==================== GEMM producers ====================
        // Permuted wt columns (r11/r12-verified): col c=t*4+e <-> gate
        // g=(t>>2)*8+(t&3)*2+(e>>1)+(e&1)*16
        for (int idx = tid; idx < NIN * 32; idx += 256) {
            int c = idx / NIN, i = idx - c * NIN;
            int t = c >> 2, e = c & 3;
            int g = (t >> 2) * 8 + (t & 3) * 2 + (e >> 1) + ((e & 1) << 4);
            float sc = ((g >> 3) == 2) ? STANH : SSIG;
            wt[i][c] = sc * w_ih0[g * NIN + i];
        }
        if (tid < 32) {
            int c = tid, t = c >> 2, e = c & 3;
            int g = (t >> 2) * 8 + (t & 3) * 2 + (e >> 1) + ((e & 1) << 4);
            float sc = ((g >> 3) == 2) ? STANH : SSIG;
            bias[c] = sc * (b_ih0[g] + b_hh0[g]);
        }
        __syncthreads();

        const int rg = tid >> 3;      // 0..31 -> 4 rows
        const int t8 = tid & 7;
        const int toff = (t8 >> 2) * 16 + (t8 & 3) * 4;

        for (int it = bid - 64; it < 1024; it += 192) {
            const int s  = it >> 1;
            const int b0 = (it & 1) * 128 + rg * 4;
            const float* xr = x + ((size_t)s * B_ + b0) * NIN;

            v2 acc[4][2];
            #pragma unroll
            for (int r = 0; r < 4; ++r) { acc[r][0] = v2{0.f,0.f}; acc[r][1] = v2{0.f,0.f}; }

            float4 xb[4][4];
            #pragma unroll
            for (int d = 0; d < 4; ++d)
                #pragma unroll
                for (int r = 0; r < 4; ++r)
                    xb[d][r] = *(const float4*)(xr + (size_t)r * NIN + 4 * d);

            auto GSTEP = [&](int ii, int d, bool pref) {
                float4 xn[4];
                if (pref) {
                    #pragma unroll
                    for (int r = 0; r < 4; ++r)
                        xn[r] = *(const float4*)(xr + (size_t)r * NIN + 4 * (ii + 4));
                }
                #pragma unroll
                for (int e = 0; e < 4; ++e) {
                    float4 wv = *(const float4*)&wt[4 * ii + e][t8 * 4];
                    v2 wlo = v2{wv.x, wv.y}, whi = v2{wv.z, wv.w};
                    #pragma unroll
                    for (int r = 0; r < 4; ++r) {
                        float xe = (e == 0) ? xb[d][r].x : (e == 1) ? xb[d][r].y
                                 : (e == 2) ? xb[d][r].z : xb[d][r].w;
                        v2 xv = v2{xe, xe};
                        acc[r][0] = __builtin_elementwise_fma(wlo, xv, acc[r][0]);
                        acc[r][1] = __builtin_elementwise_fma(whi, xv, acc[r][1]);
                    }
                }
                if (pref) {
                    #pragma unroll
                    for (int r = 0; r < 4; ++r) xb[d][r] = xn[r];
                }
            };

            for (int r = 0; r < 10; ++r) {
                GSTEP(4 * r + 0, 0, true);
                GSTEP(4 * r + 1, 1, true);
                GSTEP(4 * r + 2, 2, true);
                GSTEP(4 * r + 3, 3, true);
            }
            GSTEP(40, 0, true);       // loads ii=44 into slot 0
            GSTEP(41, 1, false);
            GSTEP(42, 2, false);
            GSTEP(43, 3, false);
            GSTEP(44, 0, false);

            float4 bv = *(const float4*)&bias[t8 * 4];
            #pragma unroll
            for (int r = 0; r < 4; ++r) {
                int b = b0 + r;
                float4 o;
                o.x = acc[r][0].x + bv.x;
                o.y = acc[r][0].y + bv.y;
                o.z = acc[r][1].x + bv.z;
                o.w = acc[r][1].y + bv.w;
                size_t base = ((size_t)s * 64 + (b >> 2)) * 128 + (b & 3) * 32 + toff;
                *(float4*)(xg2 + base) = o;
            }

            __threadfence();
            __syncthreads();
            if (tid == 0)
                __hip_atomic_store(&flags[it], 1u, __ATOMIC_RELEASE,
                                   __HIP_MEMORY_SCOPE_AGENT);
        }
        return;
    }

    // ==================== scan block (4 waves) ====================
    const int wid = tid >> 6;          // 0=A1, 1=A2, 2=B, 3=proj
    const int lt  = tid & 63;
    const int j   = lt & 7;
    const int b3  = (lt >> 3) & 1;
    const int cc  = lt >> 4;
    const bool b3z = (b3 == 0);

    const int gA = b3 * 8 + j;
    const int gB = (2 + b3) * 8 + j;
    const float sB_ = b3z ? STANH : SSIG;
    const float aB  = b3z ? 2.0f : 1.0f;
    const float bB  = b3z ? -1.0f : 0.0f;

    auto COMBINE2 = [&](float tA, float tB, float& c, float& h) {
        float m  = tA * tB;
        float mr = dppf<ROR8>(m);
        float fa = dppf<ROR8>(tA);
        float ob = dppf<ROR8>(tB);
        float ig = b3z ? m  : mr;
        float f  = b3z ? fa : tA;
        float o  = b3z ? ob : tB;
        c = __builtin_fmaf(f, c, ig);
        float th = __builtin_fmaf(2.0f, __builtin_amdgcn_rcpf(
            1.0f + __builtin_amdgcn_exp2f(STANH * c)), -1.0f);
        h = o * th;
    };

    if (wid == 0) {
        // ----- wave A1: layer-0 recurrence (flag-gated prefetch) -----
        v2 w0p[8];
        #pragma unroll
        for (int m = 0; m < 8; ++m) {
            int k = j ^ m;
            w0p[m] = v2{SSIG * w_hh0[gA * 8 + k], sB_ * w_hh0[gB * 8 + k]};
        }
        float h0p = 0.f, c0v = 0.f;
        const int fhalf = bid >> 5;

        auto WAITROWS = [&](int base) {
            const int sidx = (((base + (lt & 7)) & 511) << 1) + fhalf;
            while (!__all(__hip_atomic_load(&flags[sidx], __ATOMIC_RELAXED,
                                            __HIP_MEMORY_SCOPE_AGENT) != 0u)) {}
            __builtin_amdgcn_fence(__ATOMIC_ACQUIRE, "agent");
        };

        const float* xbase = xg2 + (size_t)bid * 128 + lt * 2;
        WAITROWS(0);
        v2 xq[8];
        #pragma unroll
        for (int k = 0; k < 8; ++k) xq[k] = *(const v2*)(xbase + (size_t)k * 8192);

        for (int hh = 0; hh < 64; ++hh) {
            WAITROWS(8 * hh + 8);
            const float* pre = xbase + (size_t)((8 * hh + 8) & 511) * 8192;
            const int sb8 = (hh & 1) * 8;
            #pragma unroll
            for (int k = 0; k < 8; ++k) {
                v2 xc = xq[k];
                xq[k] = *(const v2*)(pre + (size_t)k * 8192);
                float r0[8];
                ROTS8(h0p, r0);
                v2 a0L = __builtin_elementwise_fma(w0p[0], v2{r0[0], r0[0]}, xc);
                v2 a0H = w0p[4] * v2{r0[4], r0[4]};
                #pragma unroll
                for (int m = 1; m < 4; ++m) {
                    a0L = __builtin_elementwise_fma(w0p[m], v2{r0[m], r0[m]}, a0L);
                    a0H = __builtin_elementwise_fma(w0p[m + 4], v2{r0[m + 4], r0[m + 4]}, a0H);
                }
                v2 a0 = a0L + a0H;
                float eA = __builtin_amdgcn_exp2f(a0.x);
                float eB = __builtin_amdgcn_exp2f(a0.y);
                float tA = __builtin_amdgcn_rcpf(1.0f + eA);
                float tB = __builtin_fmaf(aB, __builtin_amdgcn_rcpf(1.0f + eB), bB);
                COMBINE2(tA, tB, c0v, h0p);
                ring0[sb8 + k][lt] = h0p;
                if (k == 3 || k == 7) __syncthreads();   // #1..#128
            }
        }
        __syncthreads();                                  // #129
        __syncthreads();                                  // #130
    } else if (wid == 1) {
        // ----- wave A2: a1p = b1 + Wih1*h0 -----
        v2 wi1p[8];
        #pragma unroll
        for (int m = 0; m < 8; ++m) {
            int k = j ^ m;
            wi1p[m] = v2{SSIG * w_ih1[gA * 8 + k], sB_ * w_ih1[gB * 8 + k]};
        }
        const v2 b1p = v2{SSIG * (b_ih1[gA] + b_hh1[gA]),
                          sB_  * (b_ih1[gB] + b_hh1[gB])};

        __syncthreads();                                  // #1
        for (int p = 1; p <= 128; ++p) {
            const int sb = ((p - 1) & 3) * 4;
            float h0v[4];
            #pragma unroll
            for (int k = 0; k < 4; ++k) h0v[k] = ring0[sb + k][lt];
            #pragma unroll
            for (int k = 0; k < 4; ++k) {
                float r0[8];
                ROTS8(h0v[k], r0);
                v2 a = __builtin_elementwise_fma(wi1p[0], v2{r0[0], r0[0]}, b1p);
                #pragma unroll
                for (int m = 1; m < 8; ++m)
                    a = __builtin_elementwise_fma(wi1p[m], v2{r0[m], r0[m]}, a);
                *(v2*)&ring1[sb + k][lt * 2] = a;
            }
            __syncthreads();                              // #2..#129
        }
        __syncthreads();                                  // #130
    } else if (wid == 2) {
        // ----- wave B: layer-1 recurrence -> ring2 -----
        v2 wh1p[8];
        #pragma unroll
        for (int m = 0; m < 8; ++m) {
            int k = j ^ m;
            wh1p[m] = v2{SSIG * w_hh1[gA * 8 + k], sB_ * w_hh1[gB * 8 + k]};
        }
        float h1p = 0.f, c1v = 0.f;

        auto BODY4 = [&](int p) {
            const int sb = ((p - 2) & 3) * 4;
            v2 a1in[4];
            #pragma unroll
            for (int k = 0; k < 4; ++k) a1in[k] = *(const v2*)&ring1[sb + k][lt * 2];
            #pragma unroll
            for (int k = 0; k < 4; ++k) {
                float r1[8];
                ROTS8(h1p, r1);
                v2 aL = __builtin_elementwise_fma(wh1p[0], v2{r1[0], r1[0]}, a1in[k]);
                v2 aH = wh1p[4] * v2{r1[4], r1[4]};
                #pragma unroll
                for (int m = 1; m < 4; ++m) {
                    aL = __builtin_elementwise_fma(wh1p[m], v2{r1[m], r1[m]}, aL);
                    aH = __builtin_elementwise_fma(wh1p[m + 4], v2{r1[m + 4], r1[m + 4]}, aH);
                }
                v2 a1 = aL + aH;
                float eA = __builtin_amdgcn_exp2f(a1.x);
                float eB = __builtin_amdgcn_exp2f(a1.y);
                float tA = __builtin_amdgcn_rcpf(1.0f + eA);
                float tB = __builtin_fmaf(aB, __builtin_amdgcn_rcpf(1.0f + eB), bB);
                COMBINE2(tA, tB, c1v, h1p);
                ring2[sb + k][lt] = h1p;
            }
        };

        __syncthreads();                                  // #1
        __syncthreads();                                  // #2
        for (int p = 2; p <= 128; ++p) { BODY4(p); __syncthreads(); }  // #3..#129
        BODY4(129);                                       // steps 508..511
        __syncthreads();                                  // #130
    } else {
        // ----- wave W3: projection -----
        float wrl[8];
        #pragma unroll
        for (int m = 0; m < 8; ++m) wrl[m] = w_reg[b3 * 8 + (j ^ m)];
        const float br  = b_reg[b3];
        const bool isl  = (j == 0);
        const int  ooff = (bid * 4 + cc) * 2 + b3;

        auto PBODY = [&](int sb, int wbase) {
            float h1v[4];
            #pragma unroll
            for (int k = 0; k < 4; ++k) h1v[k] = ring2[sb + k][lt];
            #pragma unroll
            for (int k = 0; k < 4; ++k) {
                float r1[8];
                ROTS8(h1v[k], r1);
                float pp = br;
                #pragma unroll
                for (int m = 0; m < 8; ++m) pp = __builtin_fmaf(wrl[m], r1[m], pp);
                if (isl) out[(size_t)(wbase + k) * 512 + ooff] = pp;
            }
        };

        __syncthreads();                                  // #1
        __syncthreads();                                  // #2
        __syncthreads();                                  // #3
        for (int p = 3; p <= 129; ++p) {
            PBODY(((p - 3) & 3) * 4, 4 * (p - 3));
            __syncthreads();                              // #4..#130
        }
        PBODY(12, 508);                                   // steps 508..511
    }
}

extern "C" void kernel_launch(void* const* d_in, const int* in_sizes, int n_in,
                              void* d_out, int out_size, void* d_ws, size_t ws_size,
                              hipStream_t stream) {
    (void)in_sizes; (void)n_in; (void)out_size; (void)ws_size;
    const float* x     = (const float*)d_in[0];
    const float* w_ih0 = (const float*)d_in[1];
    const float* w_hh0 = (const float*)d_in[2];
    const float* b_ih0 = (const float*)d_in[3];
    const float* b_hh0 = (const float*)d_in[4];
    const float* w_ih1 = (const float*)d_in[5];
    const float* w_hh1 = (const float*)d_in[6];
    const float* b_ih1 = (const float*)d_in[7];
    const float* b_hh1 = (const float*)d_in[8];
    const float* w_reg = (const float*)d_in[9];
    const float* b_reg = (const float*)d_in[10];
    float* out = (float*)d_out;
    float* xg2 = (float*)d_ws;                            // 16 MB
    const size_t XG_BYTES = (size_t)S_ * 64 * 128 * 4;
    unsigned* flags = (unsigned*)((char*)d_ws + XG_BYTES); // 4 KB

    hipMemsetAsync(flags, 0, 1024 * sizeof(unsigned), stream);
    lstm_fused<<<256, 256, 0, stream>>>(x, w_ih0, b_ih0, b_hh0, w_hh0,
                                        w_ih1, w_hh1, b_ih1, b_hh1,
                                        w_reg, b_reg, xg2, flags, out);
}

// Round 14
// 136.488 us; speedup vs baseline: 1.6739x; 1.6739x over previous
//
#include <hip/hip_runtime.h>

#define S_  512
#define B_  256
#define NIN 180

typedef float v2 __attribute__((ext_vector_type(2)));

#define SSIG  -1.4426950408889634f
#define STANH -2.8853900817779268f

// ---- DPP ctrl encodings (verified on HW r5-r13) ----
#define QP_X1 0xB1
#define QP_X2 0x4E
#define QP_X3 0x1B
#define ROR4  0x124
#define ROR8  0x128

template<int CTRL>
__device__ __forceinline__ float dppf(float x) {
    return __uint_as_float((unsigned)__builtin_amdgcn_update_dpp(
        0, (int)__float_as_uint(x), CTRL, 0xF, 0xF, true));
}

#define ROTS8(h, r) do { \
    r[0] = (h); \
    r[1] = dppf<QP_X1>(h); \
    r[2] = dppf<QP_X2>(h); \
    r[3] = dppf<QP_X3>(h); \
    r[4] = dppf<ROR4>(h); \
    r[5] = dppf<QP_X1>(r[4]); \
    r[6] = dppf<QP_X2>(r[4]); \
    r[7] = dppf<QP_X3>(r[4]); \
} while (0)

// ======================= Kernel A: input GEMM v3 =======================
// Wave = (row-set, qb); lane = row. 16 gates/lane (quads qb, 2+qb) are the
// 16 contiguous floats of the scan layout: idx = ((s*64+(row>>2))*64 +
// (row&3)*16 + qb*8 + j)*2 + c  -> 4 coalesced float4 stores per lane.
// x staged via LDS [2][4][256] (e-major, conflict-free); loader = tid<256,
// one full-unique float4 per lane, depth-4 register ring (HBM-saturating).
// Weights wave-uniform -> scalar loads + SGPR-operand v_fma.
__global__ __launch_bounds__(512) void xg_gemm(
    const float* __restrict__ x, const float* __restrict__ w,
    const float* __restrict__ bi, const float* __restrict__ bh,
    float* __restrict__ xg2)
{
    __shared__ float xs[2][4][256];

    const int tid  = threadIdx.x;
    const int lane = tid & 63;
    const int qb   = __builtin_amdgcn_readfirstlane((tid >> 6) & 1);
    const int rs   = tid >> 7;            // row-set 0..3
    const int row  = rs * 64 + lane;
    const int s    = blockIdx.x;
    const bool ldr = (tid < 256);

    const float* xrp = x + ((size_t)s * B_ + tid) * NIN;   // loader row = tid

    float acc[16];
    #pragma unroll
    for (int k = 0; k < 16; ++k) acc[k] = 0.f;

    // prologue: x(0) -> xs[0]; ring r[d&3] holds x(1..4)
    float4 rr[4];
    float4 x0;
    if (ldr) {
        x0    = *(const float4*)(xrp + 0);
        rr[1] = *(const float4*)(xrp + 4);
        rr[2] = *(const float4*)(xrp + 8);
        rr[3] = *(const float4*)(xrp + 12);
        rr[0] = *(const float4*)(xrp + 16);
        xs[0][0][tid] = x0.x; xs[0][1][tid] = x0.y;
        xs[0][2][tid] = x0.z; xs[0][3][tid] = x0.w;
    }
    __syncthreads();

    auto COMP = [&](int ii, int buf) {
        float xe0 = xs[buf][0][row];
        float xe1 = xs[buf][1][row];
        float xe2 = xs[buf][2][row];
        float xe3 = xs[buf][3][row];
        #pragma unroll
        for (int jj = 0; jj < 8; ++jj) {
            float4 wA = *(const float4*)(w + (size_t)(qb * 8 + jj) * NIN + 4 * ii);
            float4 wB = *(const float4*)(w + (size_t)((2 + qb) * 8 + jj) * NIN + 4 * ii);
            acc[2*jj]   = __builtin_fmaf(wA.x, xe0, acc[2*jj]);
            acc[2*jj+1] = __builtin_fmaf(wB.x, xe0, acc[2*jj+1]);
            acc[2*jj]   = __builtin_fmaf(wA.y, xe1, acc[2*jj]);
            acc[2*jj+1] = __builtin_fmaf(wB.y, xe1, acc[2*jj+1]);
            acc[2*jj]   = __builtin_fmaf(wA.z, xe2, acc[2*jj]);
            acc[2*jj+1] = __builtin_fmaf(wB.z, xe2, acc[2*jj+1]);
            acc[2*jj]   = __builtin_fmaf(wA.w, xe3, acc[2*jj]);
            acc[2*jj+1] = __builtin_fmaf(wB.w, xe3, acc[2*jj+1]);
        }
    };

    for (int base = 0; base <= 40; base += 4) {
        #pragma unroll
        for (int p = 0; p < 4; ++p) {
            const int ii = base + p;
            if (ldr && ii < 44) {
                const int sl = (p + 1) & 3;
                float4 wv = rr[sl];                     // x(ii+1)
                xs[(ii + 1) & 1][0][tid] = wv.x;
                xs[(ii + 1) & 1][1][tid] = wv.y;
                xs[(ii + 1) & 1][2][tid] = wv.z;
                xs[(ii + 1) & 1][3][tid] = wv.w;
                if (ii <= 39)
                    rr[sl] = *(const float4*)(xrp + 4 * (ii + 5));
            }
            COMP(ii, p & 1);
            __syncthreads();
        }
    }
    COMP(44, 0);

    // epilogue: scale + bias, 4 coalesced float4 stores
    float ob[16];
    #pragma unroll
    for (int c = 0; c < 2; ++c) {
        #pragma unroll
        for (int jj = 0; jj < 8; ++jj) {
            int g = (qb + 2 * c) * 8 + jj;
            float sc = (qb == 0 && c == 1) ? STANH : SSIG;
            ob[2*jj+c] = sc * acc[2*jj+c] + sc * (bi[g] + bh[g]);
        }
    }
    float* dst = xg2 + (((size_t)s * 64 + (row >> 2)) * 64
                        + (row & 3) * 16 + qb * 8) * 2;
    #pragma unroll
    for (int k = 0; k < 4; ++k) {
        float4 o = {ob[4*k], ob[4*k+1], ob[4*k+2], ob[4*k+3]};
        *(float4*)(dst + 4 * k) = o;
    }
}

// ======================= Kernel B: 4-wave scan =======================
// r13-verified scan block (passed correctness): A1 layer0, A2 a1p,
// B layer1, W3 projection; 16-slot rings, 130 barriers per wave.
__global__ __launch_bounds__(256, 1) void lstm_scan(
    const float* __restrict__ xg,
    const float* __restrict__ w_hh0,
    const float* __restrict__ w_ih1, const float* __restrict__ w_hh1,
    const float* __restrict__ b_ih1, const float* __restrict__ b_hh1,
    const float* __restrict__ w_reg, const float* __restrict__ b_reg,
    float* __restrict__ out)
{
    __shared__ float ring0[16][64];    // h0(u) at slot u&15
    __shared__ float ring1[16][128];   // a1p(u) (v2) at slot u&15
    __shared__ float ring2[16][64];    // h1(u) at slot u&15

    const int tid = threadIdx.x;
    const int wid = tid >> 6;          // 0=A1, 1=A2, 2=B, 3=proj
    const int lt  = tid & 63;
    const int j   = lt & 7;
    const int b3  = (lt >> 3) & 1;
    const int cc  = lt >> 4;
    const bool b3z = (b3 == 0);
    const int bid = blockIdx.x;        // 0..63

    const int gA = b3 * 8 + j;
    const int gB = (2 + b3) * 8 + j;
    const float sB_ = b3z ? STANH : SSIG;
    const float aB  = b3z ? 2.0f : 1.0f;
    const float bB  = b3z ? -1.0f : 0.0f;

    auto COMBINE2 = [&](float tA, float tB, float& c, float& h) {
        float m  = tA * tB;
        float mr = dppf<ROR8>(m);
        float fa = dppf<ROR8>(tA);
        float ob = dppf<ROR8>(tB);
        float ig = b3z ? m  : mr;
        float f  = b3z ? fa : tA;
        float o  = b3z ? ob : tB;
        c = __builtin_fmaf(f, c, ig);
        float th = __builtin_fmaf(2.0f, __builtin_amdgcn_rcpf(
            1.0f + __builtin_amdgcn_exp2f(STANH * c)), -1.0f);
        h = o * th;
    };

    if (wid == 0) {
        // ----- wave A1: layer-0 recurrence -----
        v2 w0p[8];
        #pragma unroll
        for (int m = 0; m < 8; ++m) {
            int k = j ^ m;
            w0p[m] = v2{SSIG * w_hh0[gA * 8 + k], sB_ * w_hh0[gB * 8 + k]};
        }
        float h0p = 0.f, c0v = 0.f;

        const float* xbase = xg + (size_t)bid * 128 + lt * 2;
        v2 xq[8];
        #pragma unroll
        for (int k = 0; k < 8; ++k) xq[k] = *(const v2*)(xbase + (size_t)k * 8192);

        for (int hh = 0; hh < 64; ++hh) {
            const float* pre = xbase + (size_t)((8 * hh + 8) & 511) * 8192;
            const int sb8 = (hh & 1) * 8;
            #pragma unroll
            for (int k = 0; k < 8; ++k) {
                v2 xc = xq[k];
                xq[k] = *(const v2*)(pre + (size_t)k * 8192);
                float r0[8];
                ROTS8(h0p, r0);
                v2 a0L = __builtin_elementwise_fma(w0p[0], v2{r0[0], r0[0]}, xc);
                v2 a0H = w0p[4] * v2{r0[4], r0[4]};
                #pragma unroll
                for (int m = 1; m < 4; ++m) {
                    a0L = __builtin_elementwise_fma(w0p[m], v2{r0[m], r0[m]}, a0L);
                    a0H = __builtin_elementwise_fma(w0p[m + 4], v2{r0[m + 4], r0[m + 4]}, a0H);
                }
                v2 a0 = a0L + a0H;
                float eA = __builtin_amdgcn_exp2f(a0.x);
                float eB = __builtin_amdgcn_exp2f(a0.y);
                float tA = __builtin_amdgcn_rcpf(1.0f + eA);
                float tB = __builtin_fmaf(aB, __builtin_amdgcn_rcpf(1.0f + eB), bB);
                COMBINE2(tA, tB, c0v, h0p);
                ring0[sb8 + k][lt] = h0p;
                if (k == 3 || k == 7) __syncthreads();   // #1..#128
            }
        }
        __syncthreads();                                  // #129
        __syncthreads();                                  // #130
    } else if (wid == 1) {
        // ----- wave A2: a1p = b1 + Wih1*h0 -----
        v2 wi1p[8];
        #pragma unroll
        for (int m = 0; m < 8; ++m) {
            int k = j ^ m;
            wi1p[m] = v2{SSIG * w_ih1[gA * 8 + k], sB_ * w_ih1[gB * 8 + k]};
        }
        const v2 b1p = v2{SSIG * (b_ih1[gA] + b_hh1[gA]),
                          sB_  * (b_ih1[gB] + b_hh1[gB])};

        __syncthreads();                                  // #1
        for (int p = 1; p <= 128; ++p) {
            const int sb = ((p - 1) & 3) * 4;
            float h0v[4];
            #pragma unroll
            for (int k = 0; k < 4; ++k) h0v[k] = ring0[sb + k][lt];
            #pragma unroll
            for (int k = 0; k < 4; ++k) {
                float r0[8];
                ROTS8(h0v[k], r0);
                v2 a = __builtin_elementwise_fma(wi1p[0], v2{r0[0], r0[0]}, b1p);
                #pragma unroll
                for (int m = 1; m < 8; ++m)
                    a = __builtin_elementwise_fma(wi1p[m], v2{r0[m], r0[m]}, a);
                *(v2*)&ring1[sb + k][lt * 2] = a;
            }
            __syncthreads();                              // #2..#129
        }
        __syncthreads();                                  // #130
    } else if (wid == 2) {
        // ----- wave B: layer-1 recurrence -> ring2 -----
        v2 wh1p[8];
        #pragma unroll
        for (int m = 0; m < 8; ++m) {
            int k = j ^ m;
            wh1p[m] = v2{SSIG * w_hh1[gA * 8 + k], sB_ * w_hh1[gB * 8 + k]};
        }
        float h1p = 0.f, c1v = 0.f;

        auto BODY4 = [&](int p) {
            const int sb = ((p - 2) & 3) * 4;
            v2 a1in[4];
            #pragma unroll
            for (int k = 0; k < 4; ++k) a1in[k] = *(const v2*)&ring1[sb + k][lt * 2];
            #pragma unroll
            for (int k = 0; k < 4; ++k) {
                float r1[8];
                ROTS8(h1p, r1);
                v2 aL = __builtin_elementwise_fma(wh1p[0], v2{r1[0], r1[0]}, a1in[k]);
                v2 aH = wh1p[4] * v2{r1[4], r1[4]};
                #pragma unroll
                for (int m = 1; m < 4; ++m) {
                    aL = __builtin_elementwise_fma(wh1p[m], v2{r1[m], r1[m]}, aL);
                    aH = __builtin_elementwise_fma(wh1p[m + 4], v2{r1[m + 4], r1[m + 4]}, aH);
                }
                v2 a1 = aL + aH;
                float eA = __builtin_amdgcn_exp2f(a1.x);
                float eB = __builtin_amdgcn_exp2f(a1.y);
                float tA = __builtin_amdgcn_rcpf(1.0f + eA);
                float tB = __builtin_fmaf(aB, __builtin_amdgcn_rcpf(1.0f + eB), bB);
                COMBINE2(tA, tB, c1v, h1p);
                ring2[sb + k][lt] = h1p;
            }
        };

        __syncthreads();                                  // #1
        __syncthreads();                                  // #2
        for (int p = 2; p <= 128; ++p) { BODY4(p); __syncthreads(); }  // #3..#129
        BODY4(129);                                       // steps 508..511
        __syncthreads();                                  // #130
    } else {
        // ----- wave W3: projection -----
        float wrl[8];
        #pragma unroll
        for (int m = 0; m < 8; ++m) wrl[m] = w_reg[b3 * 8 + (j ^ m)];
        const float br  = b_reg[b3];
        const bool isl  = (j == 0);
        const int  ooff = (bid * 4 + cc) * 2 + b3;

        auto PBODY = [&](int sb, int wbase) {
            float h1v[4];
            #pragma unroll
            for (int k = 0; k < 4; ++k) h1v[k] = ring2[sb + k][lt];
            #pragma unroll
            for (int k = 0; k < 4; ++k) {
                float r1[8];
                ROTS8(h1v[k], r1);
                float pp = br;
                #pragma unroll
                for (int m = 0; m < 8; ++m) pp = __builtin_fmaf(wrl[m], r1[m], pp);
                if (isl) out[(size_t)(wbase + k) * 512 + ooff] = pp;
            }
        };

        __syncthreads();                                  // #1
        __syncthreads();                                  // #2
        __syncthreads();                                  // #3
        for (int p = 3; p <= 129; ++p) {
            PBODY(((p - 3) & 3) * 4, 4 * (p - 3));
            __syncthreads();                              // #4..#130
        }
        PBODY(12, 508);                                   // steps 508..511
    }
}

extern "C" void kernel_launch(void* const* d_in, const int* in_sizes, int n_in,
                              void* d_out, int out_size, void* d_ws, size_t ws_size,
                              hipStream_t stream) {
    (void)in_sizes; (void)n_in; (void)out_size; (void)ws_size;
    const float* x     = (const float*)d_in[0];
    const float* w_ih0 = (const float*)d_in[1];
    const float* w_hh0 = (const float*)d_in[2];
    const float* b_ih0 = (const float*)d_in[3];
    const float* b_hh0 = (const float*)d_in[4];
    const float* w_ih1 = (const float*)d_in[5];
    const float* w_hh1 = (const float*)d_in[6];
    const float* b_ih1 = (const float*)d_in[7];
    const float* b_hh1 = (const float*)d_in[8];
    const float* w_reg = (const float*)d_in[9];
    const float* b_reg = (const float*)d_in[10];
    float* out = (float*)d_out;
    float* xg2 = (float*)d_ws;   // 512*64*128*4 = 16 MB scratch

    xg_gemm<<<512, 512, 0, stream>>>(x, w_ih0, b_ih0, b_hh0, xg2);
    lstm_scan<<<64, 256, 0, stream>>>(xg2, w_hh0, w_ih1, w_hh1, b_ih1, b_hh1,
                                      w_reg, b_reg, out);
}

// Round 15
// 114.323 us; speedup vs baseline: 1.9984x; 1.1939x over previous
//
#include <hip/hip_runtime.h>

#define S_  512
#define B_  256
#define NIN 180

typedef float v2 __attribute__((ext_vector_type(2)));

#define SSIG  -1.4426950408889634f
#define STANH -2.8853900817779268f

// ---- DPP ctrl encodings (verified on HW r5-r14) ----
#define QP_X1 0xB1
#define QP_X2 0x4E
#define QP_X3 0x1B
#define ROR4  0x124
#define ROR8  0x128

template<int CTRL>
__device__ __forceinline__ float dppf(float x) {
    return __uint_as_float((unsigned)__builtin_amdgcn_update_dpp(
        0, (int)__float_as_uint(x), CTRL, 0xF, 0xF, true));
}

#define ROTS8(h, r) do { \
    r[0] = (h); \
    r[1] = dppf<QP_X1>(h); \
    r[2] = dppf<QP_X2>(h); \
    r[3] = dppf<QP_X3>(h); \
    r[4] = dppf<ROR4>(h); \
    r[5] = dppf<QP_X1>(r[4]); \
    r[6] = dppf<QP_X2>(r[4]); \
    r[7] = dppf<QP_X3>(r[4]); \
} while (0)

// ======================= Kernel A: input GEMM v4 =======================
// Block = 64 rows of one s. Stage x via FLAT COALESCED float4 loads into
// padded LDS xs[64][181] (row stride 181 dwords, gcd(181,32)=1 -> free
// 2-way on compute reads). Compute: lane = row; wave = (qb, j0-pair) so
// the thread's 4 gates form ONE contiguous float4 of the scan layout.
// Weights wave-uniform -> s_load_dwordx4 + SGPR-operand FMA.
__global__ __launch_bounds__(512) void xg_gemm(
    const float* __restrict__ x, const float* __restrict__ w,
    const float* __restrict__ bi, const float* __restrict__ bh,
    float* __restrict__ xg2)
{
    __shared__ float xs[64][181];

    const int tid = threadIdx.x;
    const int s   = blockIdx.x >> 2;
    const int rq  = blockIdx.x & 3;
    const int b0  = rq * 64;

    // ---- stage: coalesced (rows b0..b0+63 are 46080 contiguous floats) ----
    const float* xsrc = x + ((size_t)s * B_ + b0) * NIN;
    #pragma unroll
    for (int k = 0; k < 6; ++k) {
        int f4 = tid + k * 512;             // float4 index in [0, 2880)
        if (f4 < 2880) {
            float4 v = *(const float4*)(xsrc + 4 * (size_t)f4);
            int row = f4 / 45;
            int col = (f4 - row * 45) * 4;
            xs[row][col]     = v.x;
            xs[row][col + 1] = v.y;
            xs[row][col + 2] = v.z;
            xs[row][col + 3] = v.w;
        }
    }
    __syncthreads();

    // ---- compute ----
    const int wv   = __builtin_amdgcn_readfirstlane(tid >> 6);  // 0..7
    const int qb   = wv & 1;
    const int j0   = (wv >> 1) * 2;
    const int lane = tid & 63;
    const int b    = b0 + lane;

    const int gA0 = qb * 8 + j0;
    const int gB0 = (2 + qb) * 8 + j0;
    const float* wA0 = w + (size_t)gA0 * NIN;
    const float* wA1 = wA0 + NIN;
    const float* wB0 = w + (size_t)gB0 * NIN;
    const float* wB1 = wB0 + NIN;

    float a0 = 0.f, a1 = 0.f, a2 = 0.f, a3 = 0.f;
    #pragma unroll 9
    for (int ii = 0; ii < 45; ++ii) {
        float x0 = xs[lane][4 * ii];
        float x1 = xs[lane][4 * ii + 1];
        float x2 = xs[lane][4 * ii + 2];
        float x3 = xs[lane][4 * ii + 3];
        float4 wa = *(const float4*)(wA0 + 4 * ii);
        float4 wb = *(const float4*)(wB0 + 4 * ii);
        float4 wc = *(const float4*)(wA1 + 4 * ii);
        float4 wd = *(const float4*)(wB1 + 4 * ii);
        a0 = __builtin_fmaf(wa.x, x0, a0); a0 = __builtin_fmaf(wa.y, x1, a0);
        a0 = __builtin_fmaf(wa.z, x2, a0); a0 = __builtin_fmaf(wa.w, x3, a0);
        a1 = __builtin_fmaf(wb.x, x0, a1); a1 = __builtin_fmaf(wb.y, x1, a1);
        a1 = __builtin_fmaf(wb.z, x2, a1); a1 = __builtin_fmaf(wb.w, x3, a1);
        a2 = __builtin_fmaf(wc.x, x0, a2); a2 = __builtin_fmaf(wc.y, x1, a2);
        a2 = __builtin_fmaf(wc.z, x2, a2); a2 = __builtin_fmaf(wc.w, x3, a2);
        a3 = __builtin_fmaf(wd.x, x0, a3); a3 = __builtin_fmaf(wd.y, x1, a3);
        a3 = __builtin_fmaf(wd.z, x2, a3); a3 = __builtin_fmaf(wd.w, x3, a3);
    }

    const float scB = (qb == 0) ? STANH : SSIG;
    float bA0 = bi[gA0] + bh[gA0];
    float bA1 = bi[gA0 + 1] + bh[gA0 + 1];
    float bB0 = bi[gB0] + bh[gB0];
    float bB1 = bi[gB0 + 1] + bh[gB0 + 1];
    float4 o;
    o.x = SSIG * (a0 + bA0);
    o.y = scB  * (a1 + bB0);
    o.z = SSIG * (a2 + bA1);
    o.w = scB  * (a3 + bB1);
    float* dst = xg2 + (((size_t)s * 64 + (b >> 2)) * 64
                        + (b & 3) * 16 + qb * 8 + j0) * 2;
    *(float4*)dst = o;
}

// ======================= Kernel B: 4-wave scan =======================
// r13/r14-verified: A1 layer0, A2 a1p, B layer1, W3 projection;
// 16-slot rings, 130 barriers per wave.
__global__ __launch_bounds__(256, 1) void lstm_scan(
    const float* __restrict__ xg,
    const float* __restrict__ w_hh0,
    const float* __restrict__ w_ih1, const float* __restrict__ w_hh1,
    const float* __restrict__ b_ih1, const float* __restrict__ b_hh1,
    const float* __restrict__ w_reg, const float* __restrict__ b_reg,
    float* __restrict__ out)
{
    __shared__ float ring0[16][64];    // h0(u) at slot u&15
    __shared__ float ring1[16][128];   // a1p(u) (v2) at slot u&15
    __shared__ float ring2[16][64];    // h1(u) at slot u&15

    const int tid = threadIdx.x;
    const int wid = tid >> 6;          // 0=A1, 1=A2, 2=B, 3=proj
    const int lt  = tid & 63;
    const int j   = lt & 7;
    const int b3  = (lt >> 3) & 1;
    const int cc  = lt >> 4;
    const bool b3z = (b3 == 0);
    const int bid = blockIdx.x;        // 0..63

    const int gA = b3 * 8 + j;
    const int gB = (2 + b3) * 8 + j;
    const float sB_ = b3z ? STANH : SSIG;
    const float aB  = b3z ? 2.0f : 1.0f;
    const float bB  = b3z ? -1.0f : 0.0f;

    auto COMBINE2 = [&](float tA, float tB, float& c, float& h) {
        float m  = tA * tB;
        float mr = dppf<ROR8>(m);
        float fa = dppf<ROR8>(tA);
        float ob = dppf<ROR8>(tB);
        float ig = b3z ? m  : mr;
        float f  = b3z ? fa : tA;
        float o  = b3z ? ob : tB;
        c = __builtin_fmaf(f, c, ig);
        float th = __builtin_fmaf(2.0f, __builtin_amdgcn_rcpf(
            1.0f + __builtin_amdgcn_exp2f(STANH * c)), -1.0f);
        h = o * th;
    };

    if (wid == 0) {
        // ----- wave A1: layer-0 recurrence -----
        v2 w0p[8];
        #pragma unroll
        for (int m = 0; m < 8; ++m) {
            int k = j ^ m;
            w0p[m] = v2{SSIG * w_hh0[gA * 8 + k], sB_ * w_hh0[gB * 8 + k]};
        }
        float h0p = 0.f, c0v = 0.f;

        const float* xbase = xg + (size_t)bid * 128 + lt * 2;
        v2 xq[8];
        #pragma unroll
        for (int k = 0; k < 8; ++k) xq[k] = *(const v2*)(xbase + (size_t)k * 8192);

        for (int hh = 0; hh < 64; ++hh) {
            const float* pre = xbase + (size_t)((8 * hh + 8) & 511) * 8192;
            const int sb8 = (hh & 1) * 8;
            #pragma unroll
            for (int k = 0; k < 8; ++k) {
                v2 xc = xq[k];
                xq[k] = *(const v2*)(pre + (size_t)k * 8192);
                float r0[8];
                ROTS8(h0p, r0);
                v2 a0L = __builtin_elementwise_fma(w0p[0], v2{r0[0], r0[0]}, xc);
                v2 a0H = w0p[4] * v2{r0[4], r0[4]};
                #pragma unroll
                for (int m = 1; m < 4; ++m) {
                    a0L = __builtin_elementwise_fma(w0p[m], v2{r0[m], r0[m]}, a0L);
                    a0H = __builtin_elementwise_fma(w0p[m + 4], v2{r0[m + 4], r0[m + 4]}, a0H);
                }
                v2 a0 = a0L + a0H;
                float eA = __builtin_amdgcn_exp2f(a0.x);
                float eB = __builtin_amdgcn_exp2f(a0.y);
                float tA = __builtin_amdgcn_rcpf(1.0f + eA);
                float tB = __builtin_fmaf(aB, __builtin_amdgcn_rcpf(1.0f + eB), bB);
                COMBINE2(tA, tB, c0v, h0p);
                ring0[sb8 + k][lt] = h0p;
                if (k == 3 || k == 7) __syncthreads();   // #1..#128
            }
        }
        __syncthreads();                                  // #129
        __syncthreads();                                  // #130
    } else if (wid == 1) {
        // ----- wave A2: a1p = b1 + Wih1*h0 -----
        v2 wi1p[8];
        #pragma unroll
        for (int m = 0; m < 8; ++m) {
            int k = j ^ m;
            wi1p[m] = v2{SSIG * w_ih1[gA * 8 + k], sB_ * w_ih1[gB * 8 + k]};
        }
        const v2 b1p = v2{SSIG * (b_ih1[gA] + b_hh1[gA]),
                          sB_  * (b_ih1[gB] + b_hh1[gB])};

        __syncthreads();                                  // #1
        for (int p = 1; p <= 128; ++p) {
            const int sb = ((p - 1) & 3) * 4;
            float h0v[4];
            #pragma unroll
            for (int k = 0; k < 4; ++k) h0v[k] = ring0[sb + k][lt];
            #pragma unroll
            for (int k = 0; k < 4; ++k) {
                float r0[8];
                ROTS8(h0v[k], r0);
                v2 a = __builtin_elementwise_fma(wi1p[0], v2{r0[0], r0[0]}, b1p);
                #pragma unroll
                for (int m = 1; m < 8; ++m)
                    a = __builtin_elementwise_fma(wi1p[m], v2{r0[m], r0[m]}, a);
                *(v2*)&ring1[sb + k][lt * 2] = a;
            }
            __syncthreads();                              // #2..#129
        }
        __syncthreads();                                  // #130
    } else if (wid == 2) {
        // ----- wave B: layer-1 recurrence -> ring2 -----
        v2 wh1p[8];
        #pragma unroll
        for (int m = 0; m < 8; ++m) {
            int k = j ^ m;
            wh1p[m] = v2{SSIG * w_hh1[gA * 8 + k], sB_ * w_hh1[gB * 8 + k]};
        }
        float h1p = 0.f, c1v = 0.f;

        auto BODY4 = [&](int p) {
            const int sb = ((p - 2) & 3) * 4;
            v2 a1in[4];
            #pragma unroll
            for (int k = 0; k < 4; ++k) a1in[k] = *(const v2*)&ring1[sb + k][lt * 2];
            #pragma unroll
            for (int k = 0; k < 4; ++k) {
                float r1[8];
                ROTS8(h1p, r1);
                v2 aL = __builtin_elementwise_fma(wh1p[0], v2{r1[0], r1[0]}, a1in[k]);
                v2 aH = wh1p[4] * v2{r1[4], r1[4]};
                #pragma unroll
                for (int m = 1; m < 4; ++m) {
                    aL = __builtin_elementwise_fma(wh1p[m], v2{r1[m], r1[m]}, aL);
                    aH = __builtin_elementwise_fma(wh1p[m + 4], v2{r1[m + 4], r1[m + 4]}, aH);
                }
                v2 a1 = aL + aH;
                float eA = __builtin_amdgcn_exp2f(a1.x);
                float eB = __builtin_amdgcn_exp2f(a1.y);
                float tA = __builtin_amdgcn_rcpf(1.0f + eA);
                float tB = __builtin_fmaf(aB, __builtin_amdgcn_rcpf(1.0f + eB), bB);
                COMBINE2(tA, tB, c1v, h1p);
                ring2[sb + k][lt] = h1p;
            }
        };

        __syncthreads();                                  // #1
        __syncthreads();                                  // #2
        for (int p = 2; p <= 128; ++p) { BODY4(p); __syncthreads(); }  // #3..#129
        BODY4(129);                                       // steps 508..511
        __syncthreads();                                  // #130
    } else {
        // ----- wave W3: projection -----
        float wrl[8];
        #pragma unroll
        for (int m = 0; m < 8; ++m) wrl[m] = w_reg[b3 * 8 + (j ^ m)];
        const float br  = b_reg[b3];
        const bool isl  = (j == 0);
        const int  ooff = (bid * 4 + cc) * 2 + b3;

        auto PBODY = [&](int sb, int wbase) {
            float h1v[4];
            #pragma unroll
            for (int k = 0; k < 4; ++k) h1v[k] = ring2[sb + k][lt];
            #pragma unroll
            for (int k = 0; k < 4; ++k) {
                float r1[8];
                ROTS8(h1v[k], r1);
                float pp = br;
                #pragma unroll
                for (int m = 0; m < 8; ++m) pp = __builtin_fmaf(wrl[m], r1[m], pp);
                if (isl) out[(size_t)(wbase + k) * 512 + ooff] = pp;
            }
        };

        __syncthreads();                                  // #1
        __syncthreads();                                  // #2
        __syncthreads();                                  // #3
        for (int p = 3; p <= 129; ++p) {
            PBODY(((p - 3) & 3) * 4, 4 * (p - 3));
            __syncthreads();                              // #4..#130
        }
        PBODY(12, 508);                                   // steps 508..511
    }
}

extern "C" void kernel_launch(void* const* d_in, const int* in_sizes, int n_in,
                              void* d_out, int out_size, void* d_ws, size_t ws_size,
                              hipStream_t stream) {
    (void)in_sizes; (void)n_in; (void)out_size; (void)ws_size;
    const float* x     = (const float*)d_in[0];
    const float* w_ih0 = (const float*)d_in[1];
    const float* w_hh0 = (const float*)d_in[2];
    const float* b_ih0 = (const float*)d_in[3];
    const float* b_hh0 = (const float*)d_in[4];
    const float* w_ih1 = (const float*)d_in[5];
    const float* w_hh1 = (const float*)d_in[6];
    const float* b_ih1 = (const float*)d_in[7];
    const float* b_hh1 = (const float*)d_in[8];
    const float* w_reg = (const float*)d_in[9];
    const float* b_reg = (const float*)d_in[10];
    float* out = (float*)d_out;
    float* xg2 = (float*)d_ws;   // 512*64*128*4 = 16 MB scratch

    xg_gemm<<<2048, 512, 0, stream>>>(x, w_ih0, b_ih0, b_hh0, xg2);
    lstm_scan<<<64, 256, 0, stream>>>(xg2, w_hh0, w_ih1, w_hh1, b_ih1, b_hh1,
                                      w_reg, b_reg, out);
}